// Round 20
// baseline (242.012 us; speedup 1.0000x reference)
//
#include <hip/hip_runtime.h>
#include <math.h>

#define B_GROUPS 64
#define C_DIM 256
#define IN_DIM 512
#define EMB_DIM 512
#define NHEADS 8
#define HDIM 32

typedef __attribute__((ext_vector_type(8))) short short8v;   // 8 bf16 = 4 VGPR
typedef __attribute__((ext_vector_type(4))) float float4v;   // mfma acc

// split fp32 -> bf16 hi (truncate, residual exact) + bf16 lo (rounded)
__device__ __forceinline__ void split2(float x, short& hi, short& lo) {
  unsigned u = __float_as_uint(x);
  hi = (short)(u >> 16);
  float l = x - __uint_as_float(u & 0xffff0000u);   // exact
  unsigned ul = __float_as_uint(l);
  lo = (short)((ul + 0x8000u) >> 16);
}

// round fp32 -> nearest bf16 (half-up) — used where lo is dropped
__device__ __forceinline__ short bf16rnd(float x) {
  return (short)((__float_as_uint(x) + 0x8000u) >> 16);
}

// global -> LDS direct copy, 16B per lane (dest linear: base + lane*16)
#define GLL(src, dst) __builtin_amdgcn_global_load_lds( \
    (const __attribute__((address_space(1))) void*)(src), \
    (__attribute__((address_space(3))) void*)(dst), 16, 0, 0)

// ---------------- per-group starts via binary search ----------------
__global__ void starts_kernel(const int* __restrict__ bx, int nx,
                              const int* __restrict__ be, int ne,
                              int* __restrict__ sx, int* __restrict__ se) {
  int b = threadIdx.x;
  if (b > B_GROUPS) return;
  int lo = 0, hi = nx;
  while (lo < hi) { int mid = (lo + hi) >> 1; if (bx[mid] < b) lo = mid + 1; else hi = mid; }
  sx[b] = lo;
  lo = 0; hi = ne;
  while (lo < hi) { int mid = (lo + hi) >> 1; if (be[mid] < b) lo = mid + 1; else hi = mid; }
  se[b] = lo;
}

// ---------------- prep: round enc,x to bf16; transpose+split weights -------
__global__ __launch_bounds__(256) void prep_kernel(
    const float* __restrict__ enc, const float* __restrict__ x,
    const float* __restrict__ W1, const float* __restrict__ W2,
    const float* __restrict__ Wq, const float* __restrict__ Wk,
    const float* __restrict__ Wv, const float* __restrict__ Wp,
    const int* __restrict__ msk,
    short* __restrict__ encH, short* __restrict__ xH,
    short* __restrict__ wbuf, float* __restrict__ fbias,
    int nEnc, int nX, int nTok) {
  int gid = blockIdx.x * blockDim.x + threadIdx.x;
  int stride = gridDim.x * blockDim.x;
  for (int i = gid; i < nEnc; i += stride) encH[i] = bf16rnd(enc[i]);
  for (int i = gid; i < nX;   i += stride) xH[i]   = bf16rnd(x[i]);
  for (int i = gid; i < nTok; i += stride) fbias[i] = msk[i] ? 0.f : -1e30f;
  short* w1tH = wbuf;               short* w1tL = w1tH + 512*512;
  short* w2tH = w1tL + 512*512;     short* w2tL = w2tH + 256*512;
  short* wqtH = w2tL + 256*512;     short* wqtL = wqtH + 256*256;
  short* wktH = wqtL + 256*256;     short* wktL = wktH + 256*256;
  short* wvtH = wktL + 256*256;     short* wvtL = wvtH + 256*256;
  short* wptH = wvtL + 256*256;     short* wptL = wptH + 256*256;
  for (int i = gid; i < 512*512; i += stride) {
    int n = i >> 9, k = i & 511; short h,l;
    split2(W1[k*512 + n], h, l); w1tH[i] = h; w1tL[i] = l;
  }
  for (int i = gid; i < 256*512; i += stride) {
    int n = i >> 9, k = i & 511; short h,l;
    split2(W2[k*256 + n], h, l); w2tH[i] = h; w2tL[i] = l;
  }
  for (int i = gid; i < 256*256; i += stride) {
    int n = i >> 8, k = i & 255; int s = k*256 + n; short h,l;
    split2(Wq[s],h,l); wqtH[i]=h; wqtL[i]=l;
    split2(Wk[s],h,l); wktH[i]=h; wktL[i]=l;
    split2(Wv[s],h,l); wvtH[i]=h; wvtL[i]=l;
    split2(Wp[s],h,l); wptH[i]=h; wptL[i]=l;
  }
}

// ---------------- bf16 MFMA GEMM: 128x128 tile, 4 waves, 2-product ---------
// (R17/R19 kernel, unchanged — harness-verified.) v21 is a LAUNCH split:
// fused G1 (1152 blocks on 1024 slots -> 2 block-waves, 2nd wave 7/8-idle)
// becomes MLP1-only (768, single wave) + Q-only (384, K=256). Homogeneous
// launches, unlike R14's negative mixed-K variant.
__global__ __launch_bounds__(256) void gemm_mfma(
    const short* __restrict__ Ah0, const short* __restrict__ Wh0,
    const short* __restrict__ Wl0,
    const float* __restrict__ bias0, float* __restrict__ Cf0,
    short* __restrict__ Ch0, short* __restrict__ Cl0,
    int K0, int N0, int act0, int emit0,
    const short* __restrict__ Ah1, const short* __restrict__ Wh1,
    const short* __restrict__ Wl1,
    const float* __restrict__ bias1, float* __restrict__ Cf1,
    short* __restrict__ Ch1, short* __restrict__ Cl1,
    int K1, int N1, int act1, int emit1,
    int xsplit, int Mrows, int gx) {
  __shared__ short AsH[4096], WsH[4096], WsL[4096];   // 24KB

  // XCD-chunked bijective swizzle (nwg % 8 == 0 for all our launches)
  int nwg = gridDim.x;
  int cpx = nwg >> 3;
  int bid = blockIdx.x;
  int w = ((bid & 7) * cpx) + (bid >> 3);
  int bxi = w % gx;
  int byi = w / gx;

  const short *Ah, *Wh, *Wl; const float* bias; float* Cf; short *Ch, *Cl;
  int K, N, act, emit;
  if (bxi < xsplit) {
    Ah=Ah0; Wh=Wh0; Wl=Wl0; bias=bias0; Cf=Cf0; Ch=Ch0; Cl=Cl0;
    K=K0; N=N0; act=act0; emit=emit0;
  } else {
    bxi -= xsplit;
    Ah=Ah1; Wh=Wh1; Wl=Wl1; bias=bias1; Cf=Cf1; Ch=Ch1; Cl=Cl1;
    K=K1; N=N1; act=act1; emit=emit1;
  }
  int bm = byi * 128;
  int bn = bxi * 128;

  int tid = threadIdx.x;
  int wv = tid >> 6, lane = tid & 63;
  int wr = (wv >> 1) * 64, wc = (wv & 1) * 64;
  int laneM = lane & 15, laneK = lane >> 4;

  int Ga = wv * 128 + lane;
  int Gb = Ga + 64;
  int rA = Ga >> 2, gA = (Ga & 3) ^ ((rA >> 1) & 3);
  int rB = Gb >> 2, gB = (Gb & 3) ^ ((rB >> 1) & 3);
  const short* pAh0 = Ah + (size_t)(bm + rA) * K + gA * 8;
  const short* pAh1 = Ah + (size_t)(bm + rB) * K + gB * 8;
  const short* pWh0 = Wh + (size_t)(bn + rA) * K + gA * 8;
  const short* pWh1 = Wh + (size_t)(bn + rB) * K + gB * 8;
  const short* pWl0 = Wl + (size_t)(bn + rA) * K + gA * 8;
  const short* pWl1 = Wl + (size_t)(bn + rB) * K + gB * 8;
  short* dAH0 = AsH + wv * 1024;  short* dAH1 = dAH0 + 512;
  short* dWH0 = WsH + wv * 1024;  short* dWH1 = dWH0 + 512;
  short* dWL0 = WsL + wv * 1024;  short* dWL1 = dWL0 + 512;

  int am[4], bo[4];
#pragma unroll
  for (int m = 0; m < 4; ++m) {
    int row = wr + m * 16 + laneM;
    am[m] = row * 32 + ((laneK ^ ((row >> 1) & 3)) << 3);
  }
#pragma unroll
  for (int n = 0; n < 4; ++n) {
    int row = wc + n * 16 + laneM;
    bo[n] = row * 32 + ((laneK ^ ((row >> 1) & 3)) << 3);
  }

  float4v acc[4][4];
  float4v z4 = {0.f, 0.f, 0.f, 0.f};
#pragma unroll
  for (int m = 0; m < 4; ++m)
#pragma unroll
    for (int n = 0; n < 4; ++n) acc[m][n] = z4;

  int nsteps = K >> 5;

  // ---- prologue: stage step 0
  GLL(pAh0, dAH0); GLL(pAh1, dAH1);
  GLL(pWh0, dWH0); GLL(pWh1, dWH1);
  GLL(pWl0, dWL0); GLL(pWl1, dWL1);
  pAh0 += 32; pAh1 += 32;
  pWh0 += 32; pWh1 += 32; pWl0 += 32; pWl1 += 32;
  __syncthreads();

  for (int t = 0; t < nsteps; ++t) {
    short8v ah[4], bh[4], bl[4];
#pragma unroll
    for (int m = 0; m < 4; ++m) ah[m] = *(const short8v*)(AsH + am[m]);
#pragma unroll
    for (int n = 0; n < 4; ++n) {
      bh[n] = *(const short8v*)(WsH + bo[n]);
      bl[n] = *(const short8v*)(WsL + bo[n]);
    }
    __syncthreads();   // A: all waves' reads complete -> buffer reusable

    if (t + 1 < nsteps) {   // stage t+1 NOW; latency hides under the MFMAs
      GLL(pAh0, dAH0); GLL(pAh1, dAH1);
      GLL(pWh0, dWH0); GLL(pWh1, dWH1);
      GLL(pWl0, dWL0); GLL(pWl1, dWL1);
      pAh0 += 32; pAh1 += 32;
      pWh0 += 32; pWh1 += 32; pWl0 += 32; pWl1 += 32;
    }

    if (emit != 3) {
      // swapped: lane owns 4 consecutive output columns
#pragma unroll
      for (int m = 0; m < 4; ++m)
#pragma unroll
        for (int n = 0; n < 4; ++n) {
          acc[m][n] = __builtin_amdgcn_mfma_f32_16x16x32_bf16(bh[n], ah[m], acc[m][n], 0, 0, 0);
          acc[m][n] = __builtin_amdgcn_mfma_f32_16x16x32_bf16(bl[n], ah[m], acc[m][n], 0, 0, 0);
        }
    } else {
#pragma unroll
      for (int m = 0; m < 4; ++m)
#pragma unroll
        for (int n = 0; n < 4; ++n) {
          acc[m][n] = __builtin_amdgcn_mfma_f32_16x16x32_bf16(ah[m], bh[n], acc[m][n], 0, 0, 0);
          acc[m][n] = __builtin_amdgcn_mfma_f32_16x16x32_bf16(ah[m], bl[n], acc[m][n], 0, 0, 0);
        }
    }
    __syncthreads();   // B: vmcnt drain (loads aged by the MFMA block)
  }

  if (emit != 3) {
    // lane owns row = bm+wr+m*16+laneM, cols bn+wc+n*16+laneK*4 .. +3
#pragma unroll
    for (int m = 0; m < 4; ++m) {
      size_t row = (size_t)(bm + wr + m * 16 + laneM);
#pragma unroll
      for (int n = 0; n < 4; ++n) {
        int colb = bn + wc + n * 16 + laneK * 4;
        float4 bv4 = *(const float4*)&bias[colb];
        float o[4];
        o[0] = acc[m][n][0] + bv4.x; o[1] = acc[m][n][1] + bv4.y;
        o[2] = acc[m][n][2] + bv4.z; o[3] = acc[m][n][3] + bv4.w;
        if (act) {
#pragma unroll
          for (int r = 0; r < 4; ++r)
            o[r] = 0.5f * o[r] * (1.0f + erff(o[r] * 0.70710678118654752f));
        }
        if (emit == 0) {
          *(float4*)&Cf[row * N + colb] = make_float4(o[0], o[1], o[2], o[3]);
        } else if (emit == 1) {          // std hi-only (g)
          short hs[4];
#pragma unroll
          for (int r = 0; r < 4; ++r) hs[r] = bf16rnd(o[r]);
          *(short4*)&Ch[row * N + colb] = make_short4(hs[0], hs[1], hs[2], hs[3]);
        } else if (emit == 2) {          // head-major hi+lo (Q)
          size_t idx = ((size_t)(colb >> 5) * Mrows + row) * 32 + (colb & 31);
          short hs[4], ls[4];
#pragma unroll
          for (int r = 0; r < 4; ++r) split2(o[r], hs[r], ls[r]);
          *(short4*)&Ch[idx] = make_short4(hs[0], hs[1], hs[2], hs[3]);
          *(short4*)&Cl[idx] = make_short4(ls[0], ls[1], ls[2], ls[3]);
        } else {                         // emit 4: head-major hi-only (K)
          size_t idx = ((size_t)(colb >> 5) * Mrows + row) * 32 + (colb & 31);
          short hs[4];
#pragma unroll
          for (int r = 0; r < 4; ++r) hs[r] = bf16rnd(o[r]);
          *(short4*)&Ch[idx] = make_short4(hs[0], hs[1], hs[2], hs[3]);
        }
      }
    }
  } else {
    // emit 3 (V^T [NH][32][Mrows], hi+lo): original order; rows packed
    float bvn[4];
#pragma unroll
    for (int n = 0; n < 4; ++n) bvn[n] = bias[bn + wc + n * 16 + laneM];
#pragma unroll
    for (int m = 0; m < 4; ++m)
#pragma unroll
      for (int n = 0; n < 4; ++n) {
        int col = bn + wc + n * 16 + laneM;
        size_t row0 = (size_t)(bm + wr + m * 16 + laneK * 4);
        size_t idx = ((size_t)(col >> 5) * 32 + (col & 31)) * Mrows + row0;
        short hs[4], ls[4];
#pragma unroll
        for (int r = 0; r < 4; ++r) split2(acc[m][n][r] + bvn[n], hs[r], ls[r]);
        *(short4*)&Ch[idx] = make_short4(hs[0], hs[1], hs[2], hs[3]);
        *(short4*)&Cl[idx] = make_short4(ls[0], ls[1], ls[2], ls[3]);
      }
  }
}

// ---------------- LayerNorm over last dim (256) -> bf16 hi-only ------------
__global__ __launch_bounds__(256) void ln_kernel(const float* __restrict__ h,
    const float* __restrict__ w, const float* __restrict__ b,
    short* __restrict__ oH, int M) {
  int row = blockIdx.x * 4 + (threadIdx.x >> 6);
  int lane = threadIdx.x & 63;
  if (row >= M) return;
  float4 v = *(const float4*)&h[(size_t)row * C_DIM + lane * 4];
  float s  = v.x + v.y + v.z + v.w;
  float s2 = v.x * v.x + v.y * v.y + v.z * v.z + v.w * v.w;
#pragma unroll
  for (int off = 1; off < 64; off <<= 1) { s += __shfl_xor(s, off); s2 += __shfl_xor(s2, off); }
  float mu  = s  * (1.0f / 256.0f);
  float var = s2 * (1.0f / 256.0f) - mu * mu;
  float inv = rsqrtf(var + 1e-5f);
  float4 wv = *(const float4*)&w[lane * 4];
  float4 bv = *(const float4*)&b[lane * 4];
  float o0 = (v.x - mu) * inv * wv.x + bv.x;
  float o1 = (v.y - mu) * inv * wv.y + bv.y;
  float o2 = (v.z - mu) * inv * wv.z + bv.z;
  float o3 = (v.w - mu) * inv * wv.w + bv.w;
  size_t off = (size_t)row * C_DIM + lane * 4;
  *(short4*)&oH[off] = make_short4(bf16rnd(o0), bf16rnd(o1), bf16rnd(o2), bf16rnd(o3));
}

// ---------------- MFMA flash attention (R17, unchanged) --------------------
__global__ __launch_bounds__(256, 4) void attn_mfma(
    const short* __restrict__ qh, const short* __restrict__ ql,   // [NH][Nx][32]
    const short* __restrict__ kh,                                 // [NH][Ne][32]
    const short* __restrict__ vh, const short* __restrict__ vl,   // [NH][32][Ne]
    const int* __restrict__ sx, const int* __restrict__ se,
    const float* __restrict__ fbias,
    short* __restrict__ yH,                                       // [Nx][256]
    int Nx, int Ne) {
  __shared__ short KsH[2048];               // [64 tok][32 k], src-swizzled
  __shared__ short VsH[2048], VsL[2048];    // [32 d][64 tok], src-swizzled
  __shared__ short Ph[4][16][72];

  int bid = blockIdx.x;
  int work = ((bid & 7) << 9) + (bid >> 3);   // same (b,hd) group -> same XCD
  int qt8 = work & 7;
  int bh  = work >> 3;
  int b   = bh & 63;
  int hd  = bh >> 6;

  int xs = sx[b], lx = sx[b + 1] - xs;
  if (qt8 * 64 >= lx) return;             // BLOCK-uniform -> no barrier hazard
  int es = se[b], le = se[b + 1] - es;

  int tid = threadIdx.x;
  int wv = tid >> 6, lane = tid & 63;
  int qt = qt8 * 4 + wv;                  // this wave's 16-row q-tile
  int lm = lane & 15, lk = lane >> 4;

  // Q frag (B-operand of swapped QK^T): lane holds Q[q=lm][k=lk*8+j]
  int qa = xs + min(qt * 16 + lm, lx - 1);
  size_t qoff = ((size_t)hd * Nx + qa) * 32 + lk * 8;
  short8v qfh = *(const short8v*)(qh + qoff);
  short8v qfl = *(const short8v*)(ql + qoff);

  // staging source addresses (slot = tid; dest linear = base + tid*16B)
  int srow = tid >> 2;                         // K: token row 0..63
  int sc   = (tid & 3) ^ ((srow >> 1) & 3);    // K: swizzled k-granule
  int vd   = tid >> 3;                         // V: d row 0..31
  int vg   = (tid & 7) ^ (vd & 7);             // V: swizzled tok-granule
  const short* kbaseH = kh + (size_t)hd * Ne * 32 + srow * 32 + sc * 8;
  const short* vbaseH = vh + ((size_t)hd * 32 + vd) * Ne + vg * 8;
  const short* vbaseL = vl + ((size_t)hd * 32 + vd) * Ne + vg * 8;
  short* dK  = KsH + wv * 512;
  short* dV  = VsH + wv * 512;
  short* dVl = VsL + wv * 512;

  // frag read offsets (loop-invariant)
  int koff[4];
#pragma unroll
  for (int t = 0; t < 4; ++t)
    koff[t] = (t * 16 + lm) * 32 + ((lk ^ ((lm >> 1) & 3)) << 3);
  int voff0[2], voff1[2];
#pragma unroll
  for (int c = 0; c < 2; ++c) {
    voff0[c] = lm * 64        + (((c * 4 + lk) ^ (lm & 7)) << 3);
    voff1[c] = (16 + lm) * 64 + (((c * 4 + lk) ^ (lm & 7)) << 3);
  }

  float4v acc0 = {0.f,0.f,0.f,0.f}, acc1 = {0.f,0.f,0.f,0.f};
  float mrun = -INFINITY, lrun = 0.f;
  const float scale = 0.17677669529663689f;  // 1/sqrt(32)

  int kvend = es + le;
  for (int kb = (es >> 6) << 6; kb < kvend; kb += 64) {
    // ---- stage K/V tile into LDS (3 GLL, 12KB total per block)
    GLL(kbaseH + (size_t)kb * 32, dK);
    GLL(vbaseH + kb, dV);
    GLL(vbaseL + kb, dVl);
    float4 fb4[4];
#pragma unroll
    for (int t = 0; t < 4; ++t)
      fb4[t] = *(const float4*)(fbias + kb + t * 16 + lk * 4);
    __syncthreads();   // drains vmcnt -> staged tile visible

    // ---- swapped QK^T: S^T = K·Q^T; lane holds S[q=lm][kv=t*16+lk*4+r]
    float4v s[4];
#pragma unroll
    for (int t = 0; t < 4; ++t) {
      short8v kfh = *(const short8v*)(KsH + koff[t]);
      float4v z = {0.f,0.f,0.f,0.f};
      z = __builtin_amdgcn_mfma_f32_16x16x32_bf16(kfh, qfh, z, 0, 0, 0);
      z = __builtin_amdgcn_mfma_f32_16x16x32_bf16(kfh, qfl, z, 0, 0, 0);
      s[t] = z;
    }

    // ---- per-lane online softmax for q = lm
    float pv[4][4];
    float mloc = -INFINITY;
    bool interior = (kb >= es) && (kb + 64 <= kvend);
    if (interior) {
#pragma unroll
      for (int t = 0; t < 4; ++t) {
        float fb[4]; *(float4*)fb = fb4[t];
#pragma unroll
        for (int r = 0; r < 4; ++r) {
          float pp = s[t][r] * scale + fb[r];
          pv[t][r] = pp;
          mloc = fmaxf(mloc, pp);
        }
      }
    } else {
#pragma unroll
      for (int t = 0; t < 4; ++t) {
        float fb[4]; *(float4*)fb = fb4[t];
        int tb = kb + t * 16 + lk * 4;
#pragma unroll
        for (int r = 0; r < 4; ++r) {
          int tok = tb + r;
          float pp = (tok >= es && tok < kvend) ? s[t][r] * scale + fb[r] : -1e30f;
          pv[t][r] = pp;
          mloc = fmaxf(mloc, pp);
        }
      }
    }
    mloc = fmaxf(mloc, __shfl_xor(mloc, 16));
    mloc = fmaxf(mloc, __shfl_xor(mloc, 32));
    float mnew = fmaxf(mrun, mloc);
    float alpha = __expf(mrun - mnew);      // first tile: exp(-inf)=0
    float lloc = 0.f;
#pragma unroll
    for (int t = 0; t < 4; ++t) {
      short hs[4];
#pragma unroll
      for (int r = 0; r < 4; ++r) {
        float e = __expf(pv[t][r] - mnew);
        lloc += e;                          // fp32 BEFORE rounding (exact l)
        hs[r] = bf16rnd(e);
      }
      int kvg = 2 * t + (lk >> 1);          // granule of kv = t*16+lk*4
      int gs = (kvg - 2 * lm) & 7;          // rotate -> spread reads
      int off = gs * 8 + (lk & 1) * 4;
      *(short4*)&Ph[wv][lm][off] = make_short4(hs[0], hs[1], hs[2], hs[3]);
    }
    lloc += __shfl_xor(lloc, 16);
    lloc += __shfl_xor(lloc, 32);
    lrun = lrun * alpha + lloc;
    mrun = mnew;

    // ---- rescale acc: acc cols are q=lm — alpha applies DIRECTLY
    acc0[0] *= alpha; acc0[1] *= alpha; acc0[2] *= alpha; acc0[3] *= alpha;
    acc1[0] *= alpha; acc1[1] *= alpha; acc1[2] *= alpha; acc1[3] *= alpha;

    // ---- PV swapped: mfma(V,P) -> O[q=lm][d=lk*4+r]
#pragma unroll
    for (int c = 0; c < 2; ++c) {
      int gs = ((4 * c + lk) - 2 * lm) & 7;
      short8v pfh = *(const short8v*)&Ph[wv][lm][gs * 8];
      short8v v0h = *(const short8v*)(VsH + voff0[c]);
      short8v v0l = *(const short8v*)(VsL + voff0[c]);
      short8v v1h = *(const short8v*)(VsH + voff1[c]);
      short8v v1l = *(const short8v*)(VsL + voff1[c]);
      acc0 = __builtin_amdgcn_mfma_f32_16x16x32_bf16(v0h, pfh, acc0, 0, 0, 0);
      acc0 = __builtin_amdgcn_mfma_f32_16x16x32_bf16(v0l, pfh, acc0, 0, 0, 0);
      acc1 = __builtin_amdgcn_mfma_f32_16x16x32_bf16(v1h, pfh, acc1, 0, 0, 0);
      acc1 = __builtin_amdgcn_mfma_f32_16x16x32_bf16(v1l, pfh, acc1, 0, 0, 0);
    }
    __syncthreads();   // protect Ks/Vs for next tile's staging
  }

  // ---- output: lane owns q=qt*16+lm, d = lk*4+r and 16+lk*4+r -> short4
  int q = qt * 16 + lm;
  if (q < lx) {
    float invl = (lrun > 0.f) ? 1.0f / lrun : 0.f;
    size_t base = (size_t)(xs + q) * C_DIM + hd * HDIM;
    *(short4*)&yH[base + lk * 4] = make_short4(
        bf16rnd(acc0[0] * invl), bf16rnd(acc0[1] * invl),
        bf16rnd(acc0[2] * invl), bf16rnd(acc0[3] * invl));
    *(short4*)&yH[base + 16 + lk * 4] = make_short4(
        bf16rnd(acc1[0] * invl), bf16rnd(acc1[1] * invl),
        bf16rnd(acc1[2] * invl), bf16rnd(acc1[3] * invl));
  }
}

// ---------------- launch ----------------
extern "C" void kernel_launch(void* const* d_in, const int* in_sizes, int n_in,
                              void* d_out, int out_size, void* d_ws, size_t ws_size,
                              hipStream_t stream) {
  const float* x    = (const float*)d_in[0];
  const int*   bx   = (const int*)d_in[1];
  const int*   be   = (const int*)d_in[2];
  const float* enc  = (const float*)d_in[3];
  const int*   msk  = (const int*)d_in[4];
  const float* Wq   = (const float*)d_in[5];
  const float* bq   = (const float*)d_in[6];
  const float* Wk   = (const float*)d_in[7];
  const float* bk   = (const float*)d_in[8];
  const float* Wv   = (const float*)d_in[9];
  const float* bv   = (const float*)d_in[10];
  const float* Wp   = (const float*)d_in[11];
  const float* bp   = (const float*)d_in[12];
  const float* W1   = (const float*)d_in[13];
  const float* b1   = (const float*)d_in[14];
  const float* W2   = (const float*)d_in[15];
  const float* b2   = (const float*)d_in[16];
  const float* lnw  = (const float*)d_in[17];
  const float* lnb  = (const float*)d_in[18];
  float* out = (float*)d_out;

  int Nx = in_sizes[0] / C_DIM;    // 24576 (multiple of 128, == Ne)
  int Ne = in_sizes[3] / IN_DIM;

  char* ws = (char*)d_ws;
  int* sx = (int*)ws;
  int* se = sx + 80;

  short* encH = (short*)(ws + 4096);                 // Ne*512
  short* encL = encH + (size_t)Ne * IN_DIM;          // (unused; layout kept)
  short* xH   = encL + (size_t)Ne * IN_DIM;          // Nx*256 (later yH)
  short* xL   = xH + (size_t)Nx * C_DIM;             // (unused)
  short* gLo  = xL + (size_t)Nx * C_DIM;             // later vH|vL
  short* qHh  = gLo + (size_t)Ne * EMB_DIM;          // Nx*256
  short* qHl  = qHh + (size_t)Nx * C_DIM;            // Nx*256
  short* wbuf = qHl + (size_t)Nx * C_DIM;            // 1.31M shorts
  float* fbias = (float*)(wbuf + 1310720);           // Ne floats
  // reuses:
  short* gHi  = (short*)d_out;                       // G1 hi; dead after G2
  float* hbuf = (float*)encH;                        // enc rounds dead post-G1
  short* hsH  = encL;
  short* kH   = (short*)d_out;                       // after G2 (g dead)
  short* vH   = gLo;                                 // gLo dead after G2
  short* vL   = gLo + (size_t)Ne * C_DIM;

  short* w1tH = wbuf;               short* w1tL = w1tH + 512*512;
  short* w2tH = w1tL + 512*512;     short* w2tL = w2tH + 256*512;
  short* wqtH = w2tL + 256*512;     short* wqtL = wqtH + 256*256;
  short* wktH = wqtL + 256*256;     short* wktL = wktH + 256*256;
  short* wvtH = wktL + 256*256;     short* wvtL = wvtH + 256*256;
  short* wptH = wvtL + 256*256;     short* wptL = wptH + 256*256;

  prep_kernel<<<2048, 256, 0, stream>>>(enc, x, W1, W2, Wq, Wk, Wv, Wp, msk,
      encH, xH, wbuf, fbias, Ne * IN_DIM, Nx * C_DIM, Ne);
  starts_kernel<<<1, 128, 0, stream>>>(bx, Nx, be, Ne, sx, se);

  int gy = Nx / 128;   // 192

  // G1a: MLP1 only (768 blocks <= 1024 slots -> single block-wave)
  gemm_mfma<<<dim3(4 * gy), 256, 0, stream>>>(
      encH, w1tH, w1tL, b1, nullptr, gHi, nullptr, IN_DIM, EMB_DIM, 1, 1,
      encH, w1tH, w1tL, b1, nullptr, gHi, nullptr, IN_DIM, EMB_DIM, 1, 1,
      4, Nx, 4);

  // G1b: Q only (384 blocks, K=256, homogeneous)
  gemm_mfma<<<dim3(2 * gy), 256, 0, stream>>>(
      xH, wqtH, wqtL, bq, nullptr, qHh, qHl, C_DIM, C_DIM, 0, 2,
      xH, wqtH, wqtL, bq, nullptr, qHh, qHl, C_DIM, C_DIM, 0, 2,
      2, Nx, 2);

  // G2: h = g@W2+b2 (fp32)
  gemm_mfma<<<dim3(2 * gy), 256, 0, stream>>>(
      gHi, w2tH, w2tL, b2, hbuf, nullptr, nullptr, EMB_DIM, C_DIM, 0, 0,
      gHi, w2tH, w2tL, b2, hbuf, nullptr, nullptr, EMB_DIM, C_DIM, 0, 0,
      2, Nx, 2);

  ln_kernel<<<(Ne + 3) / 4, 256, 0, stream>>>(hbuf, lnw, lnb, hsH, Ne);

  // KV: K -> head-major hi-only ; V -> V^T hi+lo (one A pass)
  gemm_mfma<<<dim3(4 * gy), 256, 0, stream>>>(
      hsH, wktH, wktL, bk, nullptr, kH, nullptr, C_DIM, C_DIM, 0, 4,
      hsH, wvtH, wvtL, bv, nullptr, vH, vL,      C_DIM, C_DIM, 0, 3,
      2, Nx, 4);

  // MFMA attention -> y hi-only (over x region; x dead after G1b's Q)
  attn_mfma<<<dim3(4096), 256, 0, stream>>>(
      qHh, qHl, kH, vH, vL, sx, se, fbias, xH, Nx, Ne);

  // P: out = y@Wp+bp (fp32)
  gemm_mfma<<<dim3(2 * gy), 256, 0, stream>>>(
      xH, wptH, wptL, bp, out, nullptr, nullptr, C_DIM, C_DIM, 0, 0,
      xH, wptH, wptL, bp, out, nullptr, nullptr, C_DIM, C_DIM, 0, 0,
      2, Nx, 2);
}

// Round 21
// 237.338 us; speedup vs baseline: 1.0197x; 1.0197x over previous
//
#include <hip/hip_runtime.h>
#include <math.h>

#define B_GROUPS 64
#define C_DIM 256
#define IN_DIM 512
#define EMB_DIM 512
#define NHEADS 8
#define HDIM 32

typedef __attribute__((ext_vector_type(8))) short short8v;   // 8 bf16 = 4 VGPR
typedef __attribute__((ext_vector_type(4))) float float4v;   // mfma acc

// split fp32 -> bf16 hi (truncate, residual exact) + bf16 lo (rounded)
__device__ __forceinline__ void split2(float x, short& hi, short& lo) {
  unsigned u = __float_as_uint(x);
  hi = (short)(u >> 16);
  float l = x - __uint_as_float(u & 0xffff0000u);   // exact
  unsigned ul = __float_as_uint(l);
  lo = (short)((ul + 0x8000u) >> 16);
}

// round fp32 -> nearest bf16 (half-up) — used where lo is dropped
__device__ __forceinline__ short bf16rnd(float x) {
  return (short)((__float_as_uint(x) + 0x8000u) >> 16);
}

// global -> LDS direct copy, 16B per lane (dest linear: base + lane*16)
#define GLL(src, dst) __builtin_amdgcn_global_load_lds( \
    (const __attribute__((address_space(1))) void*)(src), \
    (__attribute__((address_space(3))) void*)(dst), 16, 0, 0)

// ---------------- per-group starts via binary search ----------------
__global__ void starts_kernel(const int* __restrict__ bx, int nx,
                              const int* __restrict__ be, int ne,
                              int* __restrict__ sx, int* __restrict__ se) {
  int b = threadIdx.x;
  if (b > B_GROUPS) return;
  int lo = 0, hi = nx;
  while (lo < hi) { int mid = (lo + hi) >> 1; if (bx[mid] < b) lo = mid + 1; else hi = mid; }
  sx[b] = lo;
  lo = 0; hi = ne;
  while (lo < hi) { int mid = (lo + hi) >> 1; if (be[mid] < b) lo = mid + 1; else hi = mid; }
  se[b] = lo;
}

// ---------------- prep: round enc,x to bf16; transpose+split weights -------
__global__ __launch_bounds__(256) void prep_kernel(
    const float* __restrict__ enc, const float* __restrict__ x,
    const float* __restrict__ W1, const float* __restrict__ W2,
    const float* __restrict__ Wq, const float* __restrict__ Wk,
    const float* __restrict__ Wv, const float* __restrict__ Wp,
    const int* __restrict__ msk,
    short* __restrict__ encH, short* __restrict__ xH,
    short* __restrict__ wbuf, float* __restrict__ fbias,
    int nEnc, int nX, int nTok) {
  int gid = blockIdx.x * blockDim.x + threadIdx.x;
  int stride = gridDim.x * blockDim.x;
  for (int i = gid; i < nEnc; i += stride) encH[i] = bf16rnd(enc[i]);
  for (int i = gid; i < nX;   i += stride) xH[i]   = bf16rnd(x[i]);
  for (int i = gid; i < nTok; i += stride) fbias[i] = msk[i] ? 0.f : -1e30f;
  short* w1tH = wbuf;               short* w1tL = w1tH + 512*512;
  short* w2tH = w1tL + 512*512;     short* w2tL = w2tH + 256*512;
  short* wqtH = w2tL + 256*512;     short* wqtL = wqtH + 256*256;
  short* wktH = wqtL + 256*256;     short* wktL = wktH + 256*256;
  short* wvtH = wktL + 256*256;     short* wvtL = wvtH + 256*256;
  short* wptH = wvtL + 256*256;     short* wptL = wptH + 256*256;
  for (int i = gid; i < 512*512; i += stride) {
    int n = i >> 9, k = i & 511; short h,l;
    split2(W1[k*512 + n], h, l); w1tH[i] = h; w1tL[i] = l;
  }
  for (int i = gid; i < 256*512; i += stride) {
    int n = i >> 9, k = i & 511; short h,l;
    split2(W2[k*256 + n], h, l); w2tH[i] = h; w2tL[i] = l;
  }
  for (int i = gid; i < 256*256; i += stride) {
    int n = i >> 8, k = i & 255; int s = k*256 + n; short h,l;
    split2(Wq[s],h,l); wqtH[i]=h; wqtL[i]=l;
    split2(Wk[s],h,l); wktH[i]=h; wktL[i]=l;
    split2(Wv[s],h,l); wvtH[i]=h; wvtL[i]=l;
    split2(Wp[s],h,l); wptH[i]=h; wptL[i]=l;
  }
}

// ---------------- bf16 MFMA GEMM: 128x128 tile, 4 waves, 2-product ---------
// R17/R19 kernel — terminal configuration. A hi-only, W hi+lo; R16 reorder
// (reads -> barrier-A -> stage t+1 same buffer -> MFMA -> barrier-B).
// Measured-negative variants: VGPR cap (R18 spill), launch split (R20),
// dbuf (R6), 3-product (R17 superseded).
__global__ __launch_bounds__(256) void gemm_mfma(
    const short* __restrict__ Ah0, const short* __restrict__ Wh0,
    const short* __restrict__ Wl0,
    const float* __restrict__ bias0, float* __restrict__ Cf0,
    short* __restrict__ Ch0, short* __restrict__ Cl0,
    int K0, int N0, int act0, int emit0,
    const short* __restrict__ Ah1, const short* __restrict__ Wh1,
    const short* __restrict__ Wl1,
    const float* __restrict__ bias1, float* __restrict__ Cf1,
    short* __restrict__ Ch1, short* __restrict__ Cl1,
    int K1, int N1, int act1, int emit1,
    int xsplit, int Mrows, int gx) {
  __shared__ short AsH[4096], WsH[4096], WsL[4096];   // 24KB

  // XCD-chunked bijective swizzle (nwg % 8 == 0 for all our launches)
  int nwg = gridDim.x;
  int cpx = nwg >> 3;
  int bid = blockIdx.x;
  int w = ((bid & 7) * cpx) + (bid >> 3);
  int bxi = w % gx;
  int byi = w / gx;

  const short *Ah, *Wh, *Wl; const float* bias; float* Cf; short *Ch, *Cl;
  int K, N, act, emit;
  if (bxi < xsplit) {
    Ah=Ah0; Wh=Wh0; Wl=Wl0; bias=bias0; Cf=Cf0; Ch=Ch0; Cl=Cl0;
    K=K0; N=N0; act=act0; emit=emit0;
  } else {
    bxi -= xsplit;
    Ah=Ah1; Wh=Wh1; Wl=Wl1; bias=bias1; Cf=Cf1; Ch=Ch1; Cl=Cl1;
    K=K1; N=N1; act=act1; emit=emit1;
  }
  int bm = byi * 128;
  int bn = bxi * 128;

  int tid = threadIdx.x;
  int wv = tid >> 6, lane = tid & 63;
  int wr = (wv >> 1) * 64, wc = (wv & 1) * 64;
  int laneM = lane & 15, laneK = lane >> 4;

  int Ga = wv * 128 + lane;
  int Gb = Ga + 64;
  int rA = Ga >> 2, gA = (Ga & 3) ^ ((rA >> 1) & 3);
  int rB = Gb >> 2, gB = (Gb & 3) ^ ((rB >> 1) & 3);
  const short* pAh0 = Ah + (size_t)(bm + rA) * K + gA * 8;
  const short* pAh1 = Ah + (size_t)(bm + rB) * K + gB * 8;
  const short* pWh0 = Wh + (size_t)(bn + rA) * K + gA * 8;
  const short* pWh1 = Wh + (size_t)(bn + rB) * K + gB * 8;
  const short* pWl0 = Wl + (size_t)(bn + rA) * K + gA * 8;
  const short* pWl1 = Wl + (size_t)(bn + rB) * K + gB * 8;
  short* dAH0 = AsH + wv * 1024;  short* dAH1 = dAH0 + 512;
  short* dWH0 = WsH + wv * 1024;  short* dWH1 = dWH0 + 512;
  short* dWL0 = WsL + wv * 1024;  short* dWL1 = dWL0 + 512;

  int am[4], bo[4];
#pragma unroll
  for (int m = 0; m < 4; ++m) {
    int row = wr + m * 16 + laneM;
    am[m] = row * 32 + ((laneK ^ ((row >> 1) & 3)) << 3);
  }
#pragma unroll
  for (int n = 0; n < 4; ++n) {
    int row = wc + n * 16 + laneM;
    bo[n] = row * 32 + ((laneK ^ ((row >> 1) & 3)) << 3);
  }

  float4v acc[4][4];
  float4v z4 = {0.f, 0.f, 0.f, 0.f};
#pragma unroll
  for (int m = 0; m < 4; ++m)
#pragma unroll
    for (int n = 0; n < 4; ++n) acc[m][n] = z4;

  int nsteps = K >> 5;

  // ---- prologue: stage step 0
  GLL(pAh0, dAH0); GLL(pAh1, dAH1);
  GLL(pWh0, dWH0); GLL(pWh1, dWH1);
  GLL(pWl0, dWL0); GLL(pWl1, dWL1);
  pAh0 += 32; pAh1 += 32;
  pWh0 += 32; pWh1 += 32; pWl0 += 32; pWl1 += 32;
  __syncthreads();

  for (int t = 0; t < nsteps; ++t) {
    short8v ah[4], bh[4], bl[4];
#pragma unroll
    for (int m = 0; m < 4; ++m) ah[m] = *(const short8v*)(AsH + am[m]);
#pragma unroll
    for (int n = 0; n < 4; ++n) {
      bh[n] = *(const short8v*)(WsH + bo[n]);
      bl[n] = *(const short8v*)(WsL + bo[n]);
    }
    __syncthreads();   // A: all waves' reads complete -> buffer reusable

    if (t + 1 < nsteps) {   // stage t+1 NOW; latency hides under the MFMAs
      GLL(pAh0, dAH0); GLL(pAh1, dAH1);
      GLL(pWh0, dWH0); GLL(pWh1, dWH1);
      GLL(pWl0, dWL0); GLL(pWl1, dWL1);
      pAh0 += 32; pAh1 += 32;
      pWh0 += 32; pWh1 += 32; pWl0 += 32; pWl1 += 32;
    }

    if (emit != 3) {
      // swapped: lane owns 4 consecutive output columns
#pragma unroll
      for (int m = 0; m < 4; ++m)
#pragma unroll
        for (int n = 0; n < 4; ++n) {
          acc[m][n] = __builtin_amdgcn_mfma_f32_16x16x32_bf16(bh[n], ah[m], acc[m][n], 0, 0, 0);
          acc[m][n] = __builtin_amdgcn_mfma_f32_16x16x32_bf16(bl[n], ah[m], acc[m][n], 0, 0, 0);
        }
    } else {
#pragma unroll
      for (int m = 0; m < 4; ++m)
#pragma unroll
        for (int n = 0; n < 4; ++n) {
          acc[m][n] = __builtin_amdgcn_mfma_f32_16x16x32_bf16(ah[m], bh[n], acc[m][n], 0, 0, 0);
          acc[m][n] = __builtin_amdgcn_mfma_f32_16x16x32_bf16(ah[m], bl[n], acc[m][n], 0, 0, 0);
        }
    }
    __syncthreads();   // B: vmcnt drain (loads aged by the MFMA block)
  }

  if (emit != 3) {
    // lane owns row = bm+wr+m*16+laneM, cols bn+wc+n*16+laneK*4 .. +3
#pragma unroll
    for (int m = 0; m < 4; ++m) {
      size_t row = (size_t)(bm + wr + m * 16 + laneM);
#pragma unroll
      for (int n = 0; n < 4; ++n) {
        int colb = bn + wc + n * 16 + laneK * 4;
        float4 bv4 = *(const float4*)&bias[colb];
        float o[4];
        o[0] = acc[m][n][0] + bv4.x; o[1] = acc[m][n][1] + bv4.y;
        o[2] = acc[m][n][2] + bv4.z; o[3] = acc[m][n][3] + bv4.w;
        if (act) {
#pragma unroll
          for (int r = 0; r < 4; ++r)
            o[r] = 0.5f * o[r] * (1.0f + erff(o[r] * 0.70710678118654752f));
        }
        if (emit == 0) {
          *(float4*)&Cf[row * N + colb] = make_float4(o[0], o[1], o[2], o[3]);
        } else if (emit == 1) {          // std hi-only (g)
          short hs[4];
#pragma unroll
          for (int r = 0; r < 4; ++r) hs[r] = bf16rnd(o[r]);
          *(short4*)&Ch[row * N + colb] = make_short4(hs[0], hs[1], hs[2], hs[3]);
        } else if (emit == 2) {          // head-major hi+lo (Q)
          size_t idx = ((size_t)(colb >> 5) * Mrows + row) * 32 + (colb & 31);
          short hs[4], ls[4];
#pragma unroll
          for (int r = 0; r < 4; ++r) split2(o[r], hs[r], ls[r]);
          *(short4*)&Ch[idx] = make_short4(hs[0], hs[1], hs[2], hs[3]);
          *(short4*)&Cl[idx] = make_short4(ls[0], ls[1], ls[2], ls[3]);
        } else {                         // emit 4: head-major hi-only (K)
          size_t idx = ((size_t)(colb >> 5) * Mrows + row) * 32 + (colb & 31);
          short hs[4];
#pragma unroll
          for (int r = 0; r < 4; ++r) hs[r] = bf16rnd(o[r]);
          *(short4*)&Ch[idx] = make_short4(hs[0], hs[1], hs[2], hs[3]);
        }
      }
    }
  } else {
    // emit 3 (V^T [NH][32][Mrows], hi+lo): original order; rows packed
    float bvn[4];
#pragma unroll
    for (int n = 0; n < 4; ++n) bvn[n] = bias[bn + wc + n * 16 + laneM];
#pragma unroll
    for (int m = 0; m < 4; ++m)
#pragma unroll
      for (int n = 0; n < 4; ++n) {
        int col = bn + wc + n * 16 + laneM;
        size_t row0 = (size_t)(bm + wr + m * 16 + laneK * 4);
        size_t idx = ((size_t)(col >> 5) * 32 + (col & 31)) * Mrows + row0;
        short hs[4], ls[4];
#pragma unroll
        for (int r = 0; r < 4; ++r) split2(acc[m][n][r] + bvn[n], hs[r], ls[r]);
        *(short4*)&Ch[idx] = make_short4(hs[0], hs[1], hs[2], hs[3]);
        *(short4*)&Cl[idx] = make_short4(ls[0], ls[1], ls[2], ls[3]);
      }
  }
}

// ---------------- LayerNorm over last dim (256) -> bf16 hi-only ------------
__global__ __launch_bounds__(256) void ln_kernel(const float* __restrict__ h,
    const float* __restrict__ w, const float* __restrict__ b,
    short* __restrict__ oH, int M) {
  int row = blockIdx.x * 4 + (threadIdx.x >> 6);
  int lane = threadIdx.x & 63;
  if (row >= M) return;
  float4 v = *(const float4*)&h[(size_t)row * C_DIM + lane * 4];
  float s  = v.x + v.y + v.z + v.w;
  float s2 = v.x * v.x + v.y * v.y + v.z * v.z + v.w * v.w;
#pragma unroll
  for (int off = 1; off < 64; off <<= 1) { s += __shfl_xor(s, off); s2 += __shfl_xor(s2, off); }
  float mu  = s  * (1.0f / 256.0f);
  float var = s2 * (1.0f / 256.0f) - mu * mu;
  float inv = rsqrtf(var + 1e-5f);
  float4 wv = *(const float4*)&w[lane * 4];
  float4 bv = *(const float4*)&b[lane * 4];
  float o0 = (v.x - mu) * inv * wv.x + bv.x;
  float o1 = (v.y - mu) * inv * wv.y + bv.y;
  float o2 = (v.z - mu) * inv * wv.z + bv.z;
  float o3 = (v.w - mu) * inv * wv.w + bv.w;
  size_t off = (size_t)row * C_DIM + lane * 4;
  *(short4*)&oH[off] = make_short4(bf16rnd(o0), bf16rnd(o1), bf16rnd(o2), bf16rnd(o3));
}

// ---------------- MFMA flash attention (R17, unchanged) --------------------
__global__ __launch_bounds__(256, 4) void attn_mfma(
    const short* __restrict__ qh, const short* __restrict__ ql,   // [NH][Nx][32]
    const short* __restrict__ kh,                                 // [NH][Ne][32]
    const short* __restrict__ vh, const short* __restrict__ vl,   // [NH][32][Ne]
    const int* __restrict__ sx, const int* __restrict__ se,
    const float* __restrict__ fbias,
    short* __restrict__ yH,                                       // [Nx][256]
    int Nx, int Ne) {
  __shared__ short KsH[2048];               // [64 tok][32 k], src-swizzled
  __shared__ short VsH[2048], VsL[2048];    // [32 d][64 tok], src-swizzled
  __shared__ short Ph[4][16][72];

  int bid = blockIdx.x;
  int work = ((bid & 7) << 9) + (bid >> 3);   // same (b,hd) group -> same XCD
  int qt8 = work & 7;
  int bh  = work >> 3;
  int b   = bh & 63;
  int hd  = bh >> 6;

  int xs = sx[b], lx = sx[b + 1] - xs;
  if (qt8 * 64 >= lx) return;             // BLOCK-uniform -> no barrier hazard
  int es = se[b], le = se[b + 1] - es;

  int tid = threadIdx.x;
  int wv = tid >> 6, lane = tid & 63;
  int qt = qt8 * 4 + wv;                  // this wave's 16-row q-tile
  int lm = lane & 15, lk = lane >> 4;

  // Q frag (B-operand of swapped QK^T): lane holds Q[q=lm][k=lk*8+j]
  int qa = xs + min(qt * 16 + lm, lx - 1);
  size_t qoff = ((size_t)hd * Nx + qa) * 32 + lk * 8;
  short8v qfh = *(const short8v*)(qh + qoff);
  short8v qfl = *(const short8v*)(ql + qoff);

  // staging source addresses (slot = tid; dest linear = base + tid*16B)
  int srow = tid >> 2;                         // K: token row 0..63
  int sc   = (tid & 3) ^ ((srow >> 1) & 3);    // K: swizzled k-granule
  int vd   = tid >> 3;                         // V: d row 0..31
  int vg   = (tid & 7) ^ (vd & 7);             // V: swizzled tok-granule
  const short* kbaseH = kh + (size_t)hd * Ne * 32 + srow * 32 + sc * 8;
  const short* vbaseH = vh + ((size_t)hd * 32 + vd) * Ne + vg * 8;
  const short* vbaseL = vl + ((size_t)hd * 32 + vd) * Ne + vg * 8;
  short* dK  = KsH + wv * 512;
  short* dV  = VsH + wv * 512;
  short* dVl = VsL + wv * 512;

  // frag read offsets (loop-invariant)
  int koff[4];
#pragma unroll
  for (int t = 0; t < 4; ++t)
    koff[t] = (t * 16 + lm) * 32 + ((lk ^ ((lm >> 1) & 3)) << 3);
  int voff0[2], voff1[2];
#pragma unroll
  for (int c = 0; c < 2; ++c) {
    voff0[c] = lm * 64        + (((c * 4 + lk) ^ (lm & 7)) << 3);
    voff1[c] = (16 + lm) * 64 + (((c * 4 + lk) ^ (lm & 7)) << 3);
  }

  float4v acc0 = {0.f,0.f,0.f,0.f}, acc1 = {0.f,0.f,0.f,0.f};
  float mrun = -INFINITY, lrun = 0.f;
  const float scale = 0.17677669529663689f;  // 1/sqrt(32)

  int kvend = es + le;
  for (int kb = (es >> 6) << 6; kb < kvend; kb += 64) {
    // ---- stage K/V tile into LDS (3 GLL, 12KB total per block)
    GLL(kbaseH + (size_t)kb * 32, dK);
    GLL(vbaseH + kb, dV);
    GLL(vbaseL + kb, dVl);
    float4 fb4[4];
#pragma unroll
    for (int t = 0; t < 4; ++t)
      fb4[t] = *(const float4*)(fbias + kb + t * 16 + lk * 4);
    __syncthreads();   // drains vmcnt -> staged tile visible

    // ---- swapped QK^T: S^T = K·Q^T; lane holds S[q=lm][kv=t*16+lk*4+r]
    float4v s[4];
#pragma unroll
    for (int t = 0; t < 4; ++t) {
      short8v kfh = *(const short8v*)(KsH + koff[t]);
      float4v z = {0.f,0.f,0.f,0.f};
      z = __builtin_amdgcn_mfma_f32_16x16x32_bf16(kfh, qfh, z, 0, 0, 0);
      z = __builtin_amdgcn_mfma_f32_16x16x32_bf16(kfh, qfl, z, 0, 0, 0);
      s[t] = z;
    }

    // ---- per-lane online softmax for q = lm
    float pv[4][4];
    float mloc = -INFINITY;
    bool interior = (kb >= es) && (kb + 64 <= kvend);
    if (interior) {
#pragma unroll
      for (int t = 0; t < 4; ++t) {
        float fb[4]; *(float4*)fb = fb4[t];
#pragma unroll
        for (int r = 0; r < 4; ++r) {
          float pp = s[t][r] * scale + fb[r];
          pv[t][r] = pp;
          mloc = fmaxf(mloc, pp);
        }
      }
    } else {
#pragma unroll
      for (int t = 0; t < 4; ++t) {
        float fb[4]; *(float4*)fb = fb4[t];
        int tb = kb + t * 16 + lk * 4;
#pragma unroll
        for (int r = 0; r < 4; ++r) {
          int tok = tb + r;
          float pp = (tok >= es && tok < kvend) ? s[t][r] * scale + fb[r] : -1e30f;
          pv[t][r] = pp;
          mloc = fmaxf(mloc, pp);
        }
      }
    }
    mloc = fmaxf(mloc, __shfl_xor(mloc, 16));
    mloc = fmaxf(mloc, __shfl_xor(mloc, 32));
    float mnew = fmaxf(mrun, mloc);
    float alpha = __expf(mrun - mnew);      // first tile: exp(-inf)=0
    float lloc = 0.f;
#pragma unroll
    for (int t = 0; t < 4; ++t) {
      short hs[4];
#pragma unroll
      for (int r = 0; r < 4; ++r) {
        float e = __expf(pv[t][r] - mnew);
        lloc += e;                          // fp32 BEFORE rounding (exact l)
        hs[r] = bf16rnd(e);
      }
      int kvg = 2 * t + (lk >> 1);          // granule of kv = t*16+lk*4
      int gs = (kvg - 2 * lm) & 7;          // rotate -> spread reads
      int off = gs * 8 + (lk & 1) * 4;
      *(short4*)&Ph[wv][lm][off] = make_short4(hs[0], hs[1], hs[2], hs[3]);
    }
    lloc += __shfl_xor(lloc, 16);
    lloc += __shfl_xor(lloc, 32);
    lrun = lrun * alpha + lloc;
    mrun = mnew;

    // ---- rescale acc: acc cols are q=lm — alpha applies DIRECTLY
    acc0[0] *= alpha; acc0[1] *= alpha; acc0[2] *= alpha; acc0[3] *= alpha;
    acc1[0] *= alpha; acc1[1] *= alpha; acc1[2] *= alpha; acc1[3] *= alpha;

    // ---- PV swapped: mfma(V,P) -> O[q=lm][d=lk*4+r]
#pragma unroll
    for (int c = 0; c < 2; ++c) {
      int gs = ((4 * c + lk) - 2 * lm) & 7;
      short8v pfh = *(const short8v*)&Ph[wv][lm][gs * 8];
      short8v v0h = *(const short8v*)(VsH + voff0[c]);
      short8v v0l = *(const short8v*)(VsL + voff0[c]);
      short8v v1h = *(const short8v*)(VsH + voff1[c]);
      short8v v1l = *(const short8v*)(VsL + voff1[c]);
      acc0 = __builtin_amdgcn_mfma_f32_16x16x32_bf16(v0h, pfh, acc0, 0, 0, 0);
      acc0 = __builtin_amdgcn_mfma_f32_16x16x32_bf16(v0l, pfh, acc0, 0, 0, 0);
      acc1 = __builtin_amdgcn_mfma_f32_16x16x32_bf16(v1h, pfh, acc1, 0, 0, 0);
      acc1 = __builtin_amdgcn_mfma_f32_16x16x32_bf16(v1l, pfh, acc1, 0, 0, 0);
    }
    __syncthreads();   // protect Ks/Vs for next tile's staging
  }

  // ---- output: lane owns q=qt*16+lm, d = lk*4+r and 16+lk*4+r -> short4
  int q = qt * 16 + lm;
  if (q < lx) {
    float invl = (lrun > 0.f) ? 1.0f / lrun : 0.f;
    size_t base = (size_t)(xs + q) * C_DIM + hd * HDIM;
    *(short4*)&yH[base + lk * 4] = make_short4(
        bf16rnd(acc0[0] * invl), bf16rnd(acc0[1] * invl),
        bf16rnd(acc0[2] * invl), bf16rnd(acc0[3] * invl));
    *(short4*)&yH[base + 16 + lk * 4] = make_short4(
        bf16rnd(acc1[0] * invl), bf16rnd(acc1[1] * invl),
        bf16rnd(acc1[2] * invl), bf16rnd(acc1[3] * invl));
  }
}

// ---------------- launch (R19 schedule — terminal) ----------------
extern "C" void kernel_launch(void* const* d_in, const int* in_sizes, int n_in,
                              void* d_out, int out_size, void* d_ws, size_t ws_size,
                              hipStream_t stream) {
  const float* x    = (const float*)d_in[0];
  const int*   bx   = (const int*)d_in[1];
  const int*   be   = (const int*)d_in[2];
  const float* enc  = (const float*)d_in[3];
  const int*   msk  = (const int*)d_in[4];
  const float* Wq   = (const float*)d_in[5];
  const float* bq   = (const float*)d_in[6];
  const float* Wk   = (const float*)d_in[7];
  const float* bk   = (const float*)d_in[8];
  const float* Wv   = (const float*)d_in[9];
  const float* bv   = (const float*)d_in[10];
  const float* Wp   = (const float*)d_in[11];
  const float* bp   = (const float*)d_in[12];
  const float* W1   = (const float*)d_in[13];
  const float* b1   = (const float*)d_in[14];
  const float* W2   = (const float*)d_in[15];
  const float* b2   = (const float*)d_in[16];
  const float* lnw  = (const float*)d_in[17];
  const float* lnb  = (const float*)d_in[18];
  float* out = (float*)d_out;

  int Nx = in_sizes[0] / C_DIM;    // 24576 (multiple of 128, == Ne)
  int Ne = in_sizes[3] / IN_DIM;

  char* ws = (char*)d_ws;
  int* sx = (int*)ws;
  int* se = sx + 80;

  short* encH = (short*)(ws + 4096);                 // Ne*512
  short* encL = encH + (size_t)Ne * IN_DIM;          // (unused; layout kept)
  short* xH   = encL + (size_t)Ne * IN_DIM;          // Nx*256 (later yH)
  short* xL   = xH + (size_t)Nx * C_DIM;             // (unused)
  short* gLo  = xL + (size_t)Nx * C_DIM;             // later vH|vL
  short* qHh  = gLo + (size_t)Ne * EMB_DIM;          // Nx*256
  short* qHl  = qHh + (size_t)Nx * C_DIM;            // Nx*256
  short* wbuf = qHl + (size_t)Nx * C_DIM;            // 1.31M shorts
  float* fbias = (float*)(wbuf + 1310720);           // Ne floats
  // reuses:
  short* gHi  = (short*)d_out;                       // G1 hi; dead after G2
  float* hbuf = (float*)encH;                        // enc rounds dead post-G1
  short* hsH  = encL;
  short* kH   = (short*)d_out;                       // after G2 (g dead)
  short* vH   = gLo;                                 // gLo dead after G2
  short* vL   = gLo + (size_t)Ne * C_DIM;

  short* w1tH = wbuf;               short* w1tL = w1tH + 512*512;
  short* w2tH = w1tL + 512*512;     short* w2tL = w2tH + 256*512;
  short* wqtH = w2tL + 256*512;     short* wqtL = wqtH + 256*256;
  short* wktH = wqtL + 256*256;     short* wktL = wktH + 256*256;
  short* wvtH = wktL + 256*256;     short* wvtL = wvtH + 256*256;
  short* wptH = wvtL + 256*256;     short* wptL = wptH + 256*256;

  prep_kernel<<<2048, 256, 0, stream>>>(enc, x, W1, W2, Wq, Wk, Wv, Wp, msk,
      encH, xH, wbuf, fbias, Ne * IN_DIM, Nx * C_DIM, Ne);
  starts_kernel<<<1, 128, 0, stream>>>(bx, Nx, be, Ne, sx, se);

  int gy = Nx / 128;   // 192

  // G1: g = GELU(enc@W1+b1) -> hi-only ; Q: x@Wq+bq -> head-major hi+lo
  gemm_mfma<<<dim3(6 * gy), 256, 0, stream>>>(
      encH, w1tH, w1tL, b1, nullptr, gHi, nullptr, IN_DIM, EMB_DIM, 1, 1,
      xH,   wqtH, wqtL, bq, nullptr, qHh, qHl,     C_DIM,  C_DIM,  0, 2,
      4, Nx, 6);

  // G2: h = g@W2+b2 (fp32)
  gemm_mfma<<<dim3(2 * gy), 256, 0, stream>>>(
      gHi, w2tH, w2tL, b2, hbuf, nullptr, nullptr, EMB_DIM, C_DIM, 0, 0,
      gHi, w2tH, w2tL, b2, hbuf, nullptr, nullptr, EMB_DIM, C_DIM, 0, 0,
      2, Nx, 2);

  ln_kernel<<<(Ne + 3) / 4, 256, 0, stream>>>(hbuf, lnw, lnb, hsH, Ne);

  // KV: K -> head-major hi-only ; V -> V^T hi+lo (one A pass)
  gemm_mfma<<<dim3(4 * gy), 256, 0, stream>>>(
      hsH, wktH, wktL, bk, nullptr, kH, nullptr, C_DIM, C_DIM, 0, 4,
      hsH, wvtH, wvtL, bv, nullptr, vH, vL,      C_DIM, C_DIM, 0, 3,
      2, Nx, 4);

  // MFMA attention -> y hi-only (over x region; x dead after G1's Q)
  attn_mfma<<<dim3(4096), 256, 0, stream>>>(
      qHh, qHl, kH, vH, vL, sx, se, fbias, xH, Nx, Ne);

  // P: out = y@Wp+bp (fp32)
  gemm_mfma<<<dim3(2 * gy), 256, 0, stream>>>(
      xH, wptH, wptL, bp, out, nullptr, nullptr, C_DIM, C_DIM, 0, 0,
      xH, wptH, wptL, bp, out, nullptr, nullptr, C_DIM, C_DIM, 0, 0,
      2, Nx, 2);
}